// Round 1
// baseline (253.096 us; speedup 1.0000x reference)
//
#include <hip/hip_runtime.h>
#include <hip/hip_bf16.h>

#define GAT_ALPHA 0.2f
#define LOG2E 1.4426950408889634f

typedef float f32x4 __attribute__((ext_vector_type(4)));
typedef int   i32x4 __attribute__((ext_vector_type(4)));
typedef short bf16x8 __attribute__((ext_vector_type(8)));

static constexpr int Nn  = 2048;
static constexpr int FIN = 256;
static constexpr int FO  = 128;

static __device__ __forceinline__ unsigned short f2bf(float x) {
    __hip_bfloat16 h = __float2bfloat16(x);
    return __builtin_bit_cast(unsigned short, h);
}
static __device__ __forceinline__ float bf2f(unsigned short u) {
    unsigned int v = ((unsigned int)u) << 16;
    return __builtin_bit_cast(float, v);
}

// ---------------------------------------------------------------------------
// Kernel 0 (prep): wa = W@a (both halves). Inits md_key[8] = 0 (key of -inf).
// ---------------------------------------------------------------------------
__global__ __launch_bounds__(256) void gat_prep(
        const float* __restrict__ W, const float* __restrict__ a,
        float* __restrict__ wa, unsigned int* __restrict__ md_key)
{
    __shared__ float pr[32][8];
    __shared__ float pd[32][8];
    const int t = threadIdx.x;
    const int kl = t >> 3, seg = t & 7;
    const int k = blockIdx.x * 32 + kl;
    float ps = 0.f, pv = 0.f;
    const float* wr = W + (size_t)k * FO + seg * 16;
    #pragma unroll
    for (int f = 0; f < 16; f += 4) {
        f32x4 wv = *(const f32x4*)(wr + f);
        f32x4 as = *(const f32x4*)(a + seg * 16 + f);
        f32x4 ad = *(const f32x4*)(a + FO + seg * 16 + f);
        ps += wv[0]*as[0] + wv[1]*as[1] + wv[2]*as[2] + wv[3]*as[3];
        pv += wv[0]*ad[0] + wv[1]*ad[1] + wv[2]*ad[2] + wv[3]*ad[3];
    }
    pr[kl][seg] = ps; pd[kl][seg] = pv;
    __syncthreads();
    if (t < 32) {
        float s = 0.f, d = 0.f;
        #pragma unroll
        for (int j = 0; j < 8; ++j) { s += pr[t][j]; d += pd[t][j]; }
        wa[blockIdx.x * 32 + t]       = s;
        wa[256 + blockIdx.x * 32 + t] = d;
    }
    if (blockIdx.x == 0 && t < 8) md_key[t] = 0u;   // key(-inf)
}

// ---------------------------------------------------------------------------
// Kernel 1: WhT[b][f][n] = bf16(h@W) via MFMA; s_src/s_dst fp32-exact via wa;
// per-batch max(s_dst) via order-preserving uint atomicMax.
// ---------------------------------------------------------------------------
__global__ __launch_bounds__(256) void gat_wh(
        const float* __restrict__ h, const float* __restrict__ W,
        const float* __restrict__ wa, unsigned short* __restrict__ WhT,
        float* __restrict__ s_src, float* __restrict__ s_dst,
        unsigned int* __restrict__ md_key)
{
    __shared__ unsigned short WT[FO][264];  // [f][k] bf16, padded
    __shared__ float wal[512];
    __shared__ float sred[64][4][2];
    __shared__ float red64[64];
    const int t  = threadIdx.x;
    const int b  = blockIdx.x & 7;
    const int n0 = (blockIdx.x >> 3) << 6;

    if (t < 128) *(f32x4*)&wal[t * 4] = *(const f32x4*)&wa[t * 4];
    #pragma unroll
    for (int c = 0; c < 32; ++c) {
        int flat = c * 1024 + t * 4;
        int k = flat >> 7, f = flat & 127;
        f32x4 wv = *(const f32x4*)&W[flat];
        WT[f + 0][k] = f2bf(wv[0]);
        WT[f + 1][k] = f2bf(wv[1]);
        WT[f + 2][k] = f2bf(wv[2]);
        WT[f + 3][k] = f2bf(wv[3]);
    }
    __syncthreads();

    {
        const int row = t >> 2, seg = t & 3;
        const float* hp  = h + ((size_t)(b * Nn + n0 + row)) * FIN + seg * 64;
        const float* was = &wal[seg * 64];
        const float* wad = &wal[256 + seg * 64];
        float ps = 0.f, pv = 0.f;
        #pragma unroll
        for (int j = 0; j < 64; j += 4) {
            f32x4 hv = *(const f32x4*)(hp + j);
            f32x4 sv = *(const f32x4*)(was + j);
            f32x4 dv = *(const f32x4*)(wad + j);
            ps += hv[0]*sv[0] + hv[1]*sv[1] + hv[2]*sv[2] + hv[3]*sv[3];
            pv += hv[0]*dv[0] + hv[1]*dv[1] + hv[2]*dv[2] + hv[3]*dv[3];
        }
        sred[row][seg][0] = ps;
        sred[row][seg][1] = pv;
    }
    __syncthreads();
    if (t < 64) {
        float s = sred[t][0][0] + sred[t][1][0] + sred[t][2][0] + sred[t][3][0];
        float d = sred[t][0][1] + sred[t][1][1] + sred[t][2][1] + sred[t][3][1];
        s_src[b * Nn + n0 + t] = s;
        s_dst[b * Nn + n0 + t] = d;
        red64[t] = d;
    }
    __syncthreads();
    if (t < 16) red64[t] = fmaxf(fmaxf(red64[t], red64[t + 16]),
                                 fmaxf(red64[t + 32], red64[t + 48]));
    __syncthreads();
    if (t == 0) {
        float m = red64[0];
        #pragma unroll
        for (int j = 1; j < 16; ++j) m = fmaxf(m, red64[j]);
        unsigned int bits = __builtin_bit_cast(unsigned int, m);
        unsigned int key  = (bits & 0x80000000u) ? ~bits : (bits | 0x80000000u);
        atomicMax(md_key + b, key);
    }

    const int w = t >> 6, lane = t & 63, n16 = lane & 15, quad = lane >> 4;
    const float* ha = h + ((size_t)(b * Nn + n0 + w * 16 + n16)) * FIN + quad * 8;
    f32x4 acc[8] = {};
    #pragma unroll
    for (int ks = 0; ks < 8; ++ks) {
        f32x4 h0 = *(const f32x4*)(ha + ks * 32);
        f32x4 h1 = *(const f32x4*)(ha + ks * 32 + 4);
        bf16x8 af;
        af[0] = (short)f2bf(h0[0]); af[1] = (short)f2bf(h0[1]);
        af[2] = (short)f2bf(h0[2]); af[3] = (short)f2bf(h0[3]);
        af[4] = (short)f2bf(h1[0]); af[5] = (short)f2bf(h1[1]);
        af[6] = (short)f2bf(h1[2]); af[7] = (short)f2bf(h1[3]);
        #pragma unroll
        for (int nt = 0; nt < 8; ++nt) {
            bf16x8 bfr = *(const bf16x8*)&WT[nt * 16 + n16][ks * 32 + quad * 8];
            acc[nt] = __builtin_amdgcn_mfma_f32_16x16x32_bf16(af, bfr, acc[nt], 0, 0, 0);
        }
    }
    #pragma unroll
    for (int nt = 0; nt < 8; ++nt) {
        ushort4 pk;
        pk.x = f2bf(acc[nt][0]); pk.y = f2bf(acc[nt][1]);
        pk.z = f2bf(acc[nt][2]); pk.w = f2bf(acc[nt][3]);
        *(ushort4*)&WhT[((size_t)(b * FO + nt * 16 + n16)) * Nn + n0 + w * 16 + quad * 4] = pk;
    }
}

// ---------------------------------------------------------------------------
// Kernel 2 (v4): barrier-free register-fragment dataflow.
// 512 blocks = 64 i-tiles(32 rows) x 8 batches; wave w owns j-window w*32
// of each 128-j tile. Per lane (n16,quad):
//   - A fragment (P) computed IN REGISTERS in MFMA layout: rows n16 / n16+16,
//     j = j0 + w*32 + quad*8 .. +8 (adj read directly, 32B/row/lane)
//   - B fragment loaded DIRECTLY from global WhT in fragment layout (L2-hot,
//     per-XCD resident since batch == XCD under round-robin dispatch)
// No LDS, no __syncthreads in the main loop. Denominator via per-lane
// partials + shfl_xor reduce + one LDS atomic per wave at the end.
// Epilogue (cross-wave acc reduction) unchanged.
// ---------------------------------------------------------------------------
__global__ __launch_bounds__(256, 2) void gat_attn(
        const int* __restrict__ adj, const unsigned short* __restrict__ WhT,
        const float* __restrict__ s_src, const float* __restrict__ s_dst,
        const unsigned int* __restrict__ md_key, float* __restrict__ out)
{
    constexpr int AS = 132;                        // accbuf row stride (f32)
    __shared__ __align__(16) float accbuf[2 * 32 * AS];   // 33792 B
    __shared__ float l_red[32];

    const int t = threadIdx.x, w = t >> 6, lane = t & 63;
    const int n16 = lane & 15, quad = lane >> 4;
    const int b  = blockIdx.x & 7;
    const int i0 = (blockIdx.x >> 3) << 5;

    if (t < 32) l_red[t] = 0.f;
    __syncthreads();

    const unsigned int key = md_key[b];
    const unsigned int mb  = (key & 0x80000000u) ? (key ^ 0x80000000u) : ~key;
    const float mdb = __builtin_bit_cast(float, mb);

    // two rows per lane: r0 = i0+n16 (ig=0), r1 = i0+16+n16 (ig=1)
    const float ssr0 = s_src[b * Nn + i0 + n16];
    const float ssr1 = s_src[b * Nn + i0 + 16 + n16];
    const float tm0 = ssr0 + mdb, tm1 = ssr1 + mdb;
    const float mi0 = fmaxf(tm0, GAT_ALPHA * tm0) * LOG2E;  // row upper bound
    const float mi1 = fmaxf(tm1, GAT_ALPHA * tm1) * LOG2E;
    const float sL0 = ssr0 * LOG2E, sL1 = ssr1 * LOG2E;

    const int jw = (w << 5) + (quad << 3);         // lane's j offset in tile
    const int* ap0 = adj + ((size_t)(b * Nn + i0 + n16)) * Nn + jw;
    const int* ap1 = ap0 + (size_t)16 * Nn;
    const float* dptr = s_dst + b * Nn + jw;
    const unsigned short* wptr = WhT + ((size_t)(b * FO + n16)) * Nn + jw;

    f32x4 acc[2][8] = {};
    float ls0 = 0.f, ls1 = 0.f;

    // adj prefetch: tile 0
    i32x4 pa[4];
    pa[0] = *(const i32x4*)(ap0);
    pa[1] = *(const i32x4*)(ap0 + 4);
    pa[2] = *(const i32x4*)(ap1);
    pa[3] = *(const i32x4*)(ap1 + 4);

    for (int s = 0; s < 16; ++s) {
        const int j0 = s << 7;
        // B fragments direct from global (L2-hot, 16B/lane, 64B per quad-group)
        bf16x8 bfr[8];
        #pragma unroll
        for (int nt = 0; nt < 8; ++nt)
            bfr[nt] = *(const bf16x8*)(wptr + (size_t)(nt << 4) * Nn + j0);
        // d-values for this lane's 8 j's (L1/L2-hot broadcast)
        f32x4 d0 = *(const f32x4*)(dptr + j0);
        f32x4 d1 = *(const f32x4*)(dptr + j0 + 4);
        // adj prefetch for next tile (HBM stream, stays in flight through MFMA)
        const int jn = (s < 15) ? (j0 + 128) : 0;
        i32x4 na0 = *(const i32x4*)(ap0 + jn);
        i32x4 na1 = *(const i32x4*)(ap0 + jn + 4);
        i32x4 na2 = *(const i32x4*)(ap1 + jn);
        i32x4 na3 = *(const i32x4*)(ap1 + jn + 4);

        // e-compute directly into A-fragment layout (8 consecutive j per lane)
        bf16x8 af0, af1;
        #pragma unroll
        for (int j = 0; j < 4; ++j) {
            {   // row0, j low half
                float u  = __builtin_fmaf(d0[j], LOG2E, sL0);
                float lr = fmaxf(u, GAT_ALPHA * u);
                float e  = __builtin_amdgcn_exp2f(lr - mi0);
                e = (pa[0][j] > 0) ? e : 0.f;
                unsigned short us = f2bf(e);
                ls0 += bf2f(us); af0[j] = (short)us;
            }
            {   // row0, j high half
                float u  = __builtin_fmaf(d1[j], LOG2E, sL0);
                float lr = fmaxf(u, GAT_ALPHA * u);
                float e  = __builtin_amdgcn_exp2f(lr - mi0);
                e = (pa[1][j] > 0) ? e : 0.f;
                unsigned short us = f2bf(e);
                ls0 += bf2f(us); af0[4 + j] = (short)us;
            }
            {   // row1, j low half
                float u  = __builtin_fmaf(d0[j], LOG2E, sL1);
                float lr = fmaxf(u, GAT_ALPHA * u);
                float e  = __builtin_amdgcn_exp2f(lr - mi1);
                e = (pa[2][j] > 0) ? e : 0.f;
                unsigned short us = f2bf(e);
                ls1 += bf2f(us); af1[j] = (short)us;
            }
            {   // row1, j high half
                float u  = __builtin_fmaf(d1[j], LOG2E, sL1);
                float lr = fmaxf(u, GAT_ALPHA * u);
                float e  = __builtin_amdgcn_exp2f(lr - mi1);
                e = (pa[3][j] > 0) ? e : 0.f;
                unsigned short us = f2bf(e);
                ls1 += bf2f(us); af1[4 + j] = (short)us;
            }
        }
        #pragma unroll
        for (int nt = 0; nt < 8; ++nt) {
            acc[0][nt] = __builtin_amdgcn_mfma_f32_16x16x32_bf16(af0, bfr[nt], acc[0][nt], 0, 0, 0);
            acc[1][nt] = __builtin_amdgcn_mfma_f32_16x16x32_bf16(af1, bfr[nt], acc[1][nt], 0, 0, 0);
        }
        pa[0] = na0; pa[1] = na1; pa[2] = na2; pa[3] = na3;
    }

    // denominator: reduce per-lane partials across quads, one atomic per wave
    ls0 += __shfl_xor(ls0, 16); ls0 += __shfl_xor(ls0, 32);
    ls1 += __shfl_xor(ls1, 16); ls1 += __shfl_xor(ls1, 32);
    if (quad == 0) {
        atomicAdd(&l_red[n16], ls0);
        atomicAdd(&l_red[16 + n16], ls1);
    }

    // cross-wave accumulator reduction
    if (w < 2) {
        #pragma unroll
        for (int ig = 0; ig < 2; ++ig)
            #pragma unroll
            for (int nt = 0; nt < 8; ++nt)
                #pragma unroll
                for (int rr = 0; rr < 4; ++rr)
                    accbuf[(size_t)w * 32 * AS + (ig * 16 + quad * 4 + rr) * AS + nt * 16 + n16] = acc[ig][nt][rr];
    }
    __syncthreads();
    if (w >= 2) {
        #pragma unroll
        for (int ig = 0; ig < 2; ++ig)
            #pragma unroll
            for (int nt = 0; nt < 8; ++nt)
                #pragma unroll
                for (int rr = 0; rr < 4; ++rr)
                    accbuf[(size_t)(w - 2) * 32 * AS + (ig * 16 + quad * 4 + rr) * AS + nt * 16 + n16] += acc[ig][nt][rr];
    }
    __syncthreads();
    // normalize + ELU + coalesced store
    float* ob = out + ((size_t)(b * Nn + i0)) * FO;
    #pragma unroll
    for (int c = 0; c < 4; ++c) {
        int flat = c * 1024 + t * 4;
        int m = flat >> 7, f = flat & 127;
        f32x4 v0 = *(const f32x4*)&accbuf[(size_t)m * AS + f];
        f32x4 v1 = *(const f32x4*)&accbuf[(size_t)32 * AS + m * AS + f];
        float l = l_red[m];
        f32x4 o;
        #pragma unroll
        for (int j = 0; j < 4; ++j) {
            float x = (v0[j] + v1[j]) / l;
            o[j] = x > 0.f ? x : expm1f(x);
        }
        *(f32x4*)&ob[(size_t)m * FO + f] = o;
    }
}

extern "C" void kernel_launch(void* const* d_in, const int* in_sizes, int n_in,
                              void* d_out, int out_size, void* d_ws, size_t ws_size,
                              hipStream_t stream)
{
    const float* h   = (const float*)d_in[0];
    const int*   adj = (const int*)d_in[1];
    const float* W   = (const float*)d_in[2];
    const float* a   = (const float*)d_in[3];
    float* out = (float*)d_out;

    char* ws = (char*)d_ws;
    unsigned short* WhT = (unsigned short*)ws;                    // 4 MiB
    float* s_src        = (float*)(ws + 4194304);                 // 8 KiB
    float* s_dst        = (float*)(ws + 4259840);                 // 8 KiB
    float* wa           = (float*)(ws + 4325376);                 // 2 KiB
    unsigned int* md_key= (unsigned int*)(ws + 4327424);          // 32 B

    hipLaunchKernelGGL(gat_prep, dim3(8),   dim3(256), 0, stream, W, a, wa, md_key);
    hipLaunchKernelGGL(gat_wh,   dim3(256), dim3(256), 0, stream, h, W, wa, WhT, s_src, s_dst, md_key);
    hipLaunchKernelGGL(gat_attn, dim3(512), dim3(256), 0, stream, adj, WhT, s_src, s_dst, md_key, out);
}